// Round 1
// baseline (2457.761 us; speedup 1.0000x reference)
//
#include <hip/hip_runtime.h>
#include <math.h>

// Problem dims (fixed): B=2, S=2048 -> TOK=4096 tokens; H=4096; I=11008
#define TOK 4096
#define HD  4096
#define ID  11008

typedef __bf16 bf16x8 __attribute__((ext_vector_type(8)));
typedef float  f32x4  __attribute__((ext_vector_type(4)));

__device__ __forceinline__ unsigned short bf16bits(float f) {
  // truncation is exact for the exactly-representable values we convert
  // (small integers and ternary weights)
  return (unsigned short)(__float_as_uint(f) >> 16);
}

#define GLDS16(g, l) __builtin_amdgcn_global_load_lds( \
    (const __attribute__((address_space(1))) void*)(g), \
    (__attribute__((address_space(3))) void*)(l), 16, 0, 0)

// ---------------------------------------------------------------- convert ---
__global__ void conv_bf16(const float* __restrict__ in,
                          unsigned short* __restrict__ out, int n4) {
  int stride = gridDim.x * blockDim.x;
  for (int i = blockIdx.x * blockDim.x + threadIdx.x; i < n4; i += stride) {
    float4 v = ((const float4*)in)[i];
    ushort4 o;
    o.x = bf16bits(v.x); o.y = bf16bits(v.y);
    o.z = bf16bits(v.z); o.w = bf16bits(v.w);
    ((ushort4*)out)[i] = o;
  }
}

// ----------------------------------------------------------------- GEMM -----
// out[m,n] = sum_k A[m,k]*B[n,k]   (both K-major, "BT" layout)
// 128x128 tile, 4 waves (2x2 of 64x64), 4x4 MFMA 16x16x32 tiles per wave.
// MODE 0: gate GEMM -> ga = silu(acc*gate_s), store f32, sum |ga| -> sums[0]
// MODE 1: up GEMM   -> inter = clip(rint(ga/ga_s))*acc*(ga_s*up_s), store f32,
//                      sum |inter| -> sums[1]
// MODE 2: down GEMM -> plain f32 store
template<int MODE>
__global__ __launch_bounds__(256)
void gemm_bt(const unsigned short* __restrict__ A,
             const unsigned short* __restrict__ Bm,
             int M, int N, int K,
             float* __restrict__ Cout,
             const float* __restrict__ ga_in,
             const float* __restrict__ sc0,
             const float* __restrict__ sc1,
             double* __restrict__ sums,
             long long NN)
{
  __shared__ unsigned short As[4096];   // 128 rows x 32 k (bf16 bits), no pad
  __shared__ unsigned short Bs[4096];
  __shared__ double red[4];

  const int tid  = threadIdx.x;
  const int w    = tid >> 6;        // wave 0..3
  const int lane = tid & 63;
  const int wr   = lane & 15;       // row-in-16 for A/B frags; col for C/D
  const int qd   = lane >> 4;       // quad
  const int wm   = (w >> 1) << 6;   // wave m-offset in tile (0/64)
  const int wn   = (w & 1) << 6;    // wave n-offset in tile (0/64)
  const int m0   = blockIdx.y << 7;
  const int n0   = blockIdx.x << 7;

  f32x4 acc[4][4] = {};

  // staging: thread tid fills LDS bytes [tid*16, tid*16+16)
  // row = tid/4 (0..63), k-offset = (tid&3)*8 bf16; second call covers rows 64..127
  const int rowL = tid >> 2;
  const int kqL  = (tid & 3) * 8;
  const unsigned short* gA = A  + (size_t)(m0 + rowL) * K + kqL;
  const unsigned short* gB = Bm + (size_t)(n0 + rowL) * K + kqL;
  unsigned short* lA = As + (w << 9);   // wave-uniform LDS base (w*1024 B)
  unsigned short* lB = Bs + (w << 9);
  const size_t half = (size_t)64 * K;

  for (int k0 = 0; k0 < K; k0 += 32) {
    GLDS16(gA + k0,        lA);
    GLDS16(gA + k0 + half, lA + 2048);
    GLDS16(gB + k0,        lB);
    GLDS16(gB + k0 + half, lB + 2048);
    __syncthreads();   // compiler emits vmcnt(0) drain before barrier

    bf16x8 af[4], bfr[4];
#pragma unroll
    for (int i = 0; i < 4; i++)
      af[i] = *(const bf16x8*)(As + (((wm + (i << 4) + wr) << 5) + (qd << 3)));
#pragma unroll
    for (int j = 0; j < 4; j++)
      bfr[j] = *(const bf16x8*)(Bs + (((wn + (j << 4) + wr) << 5) + (qd << 3)));

#pragma unroll
    for (int i = 0; i < 4; i++)
#pragma unroll
      for (int j = 0; j < 4; j++)
        acc[i][j] = __builtin_amdgcn_mfma_f32_16x16x32_bf16(af[i], bfr[j],
                                                            acc[i][j], 0, 0, 0);
    __syncthreads();
  }

  // epilogue: C/D layout col = lane&15, row = quad*4 + reg  [m89/m91-verified]
  double lsum = 0.0;

  if (MODE == 0) {
    const float gs = sc0[0] * sc1[0];   // x_scale * ws_gate
#pragma unroll
    for (int i = 0; i < 4; i++) {
      const int mb = m0 + wm + (i << 4) + (qd << 2);
#pragma unroll
      for (int j = 0; j < 4; j++) {
        const int n = n0 + wn + (j << 4) + wr;
#pragma unroll
        for (int r = 0; r < 4; r++) {
          float g = acc[i][j][r] * gs;
          float s = g / (1.0f + expf(-g));          // silu
          Cout[(size_t)(mb + r) * N + n] = s;
          lsum += (double)fabsf(s);
        }
      }
    }
  } else if (MODE == 1) {
    const float up_s  = sc0[0] * sc1[0];            // x_scale * ws_up
    const float ga_s  = (float)(sums[0] / (double)NN) + 1e-8f;
    const float combo = ga_s * up_s;
#pragma unroll
    for (int i = 0; i < 4; i++) {
      const int mb = m0 + wm + (i << 4) + (qd << 2);
#pragma unroll
      for (int j = 0; j < 4; j++) {
        const int n = n0 + wn + (j << 4) + wr;
#pragma unroll
        for (int r = 0; r < 4; r++) {
          float up = acc[i][j][r];
          float ga = ga_in[(size_t)(mb + r) * N + n];
          float gq = fmaxf(-128.0f, fminf(127.0f, rintf(ga / ga_s)));
          float itv = gq * up * combo;
          Cout[(size_t)(mb + r) * N + n] = itv;
          lsum += (double)fabsf(itv);
        }
      }
    }
  } else {
#pragma unroll
    for (int i = 0; i < 4; i++) {
      const int mb = m0 + wm + (i << 4) + (qd << 2);
#pragma unroll
      for (int j = 0; j < 4; j++) {
        const int n = n0 + wn + (j << 4) + wr;
#pragma unroll
        for (int r = 0; r < 4; r++)
          Cout[(size_t)(mb + r) * N + n] = acc[i][j][r];
      }
    }
  }

  if (MODE != 2) {
    // wave reduce (double) then one device-scope atomic per block
    for (int off = 32; off; off >>= 1) lsum += __shfl_down(lsum, off, 64);
    if (lane == 0) red[w] = lsum;
    __syncthreads();
    if (tid == 0) atomicAdd(&sums[MODE], red[0] + red[1] + red[2] + red[3]);
  }
}

// ------------------------------------------------------------- quantize -----
__global__ void quant_inter(const float* __restrict__ inter,
                            unsigned short* __restrict__ outq,
                            const double* __restrict__ sums, long long NN,
                            const float* __restrict__ wsd,
                            float* __restrict__ scalar_out, int n4)
{
  const float is = (float)(sums[1] / (double)NN) + 1e-8f;
  if (blockIdx.x == 0 && threadIdx.x == 0) scalar_out[0] = is * wsd[0];
  int stride = gridDim.x * blockDim.x;
  for (int i = blockIdx.x * blockDim.x + threadIdx.x; i < n4; i += stride) {
    float4 v = ((const float4*)inter)[i];
    ushort4 o;
    o.x = bf16bits(fmaxf(-128.0f, fminf(127.0f, rintf(v.x / is))));
    o.y = bf16bits(fmaxf(-128.0f, fminf(127.0f, rintf(v.y / is))));
    o.z = bf16bits(fmaxf(-128.0f, fminf(127.0f, rintf(v.z / is))));
    o.w = bf16bits(fmaxf(-128.0f, fminf(127.0f, rintf(v.w / is))));
    ((ushort4*)outq)[i] = o;
  }
}

// ---------------------------------------------------------------- launch ----
extern "C" void kernel_launch(void* const* d_in, const int* in_sizes, int n_in,
                              void* d_out, int out_size, void* d_ws, size_t ws_size,
                              hipStream_t stream) {
  const float* x        = (const float*)d_in[0];
  const float* x_scale  = (const float*)d_in[1];
  const float* qw_gate  = (const float*)d_in[2];
  const float* ws_gate  = (const float*)d_in[3];
  const float* qw_up    = (const float*)d_in[4];
  const float* ws_up    = (const float*)d_in[5];
  const float* qw_down  = (const float*)d_in[6];
  const float* ws_down  = (const float*)d_in[7];
  float* out = (float*)d_out;

  char* ws = (char*)d_ws;
  double* sums = (double*)ws;                       // [0]=sum|ga| [1]=sum|inter|
  size_t off = 256;
  unsigned short* xbf  = (unsigned short*)(ws + off); off += (size_t)TOK * HD * 2;
  unsigned short* wgbf = (unsigned short*)(ws + off); off += (size_t)ID * HD * 2;
  unsigned short* wubf = (unsigned short*)(ws + off); off += (size_t)ID * HD * 2;
  unsigned short* wdbf = (unsigned short*)(ws + off); off += (size_t)HD * ID * 2;
  float* ga    = (float*)(ws + off); off += (size_t)TOK * ID * 4;
  float* inter = (float*)(ws + off); off += (size_t)TOK * ID * 4;
  unsigned short* interq = wgbf;   // reuse gate-weight buffer (dead after MODE0)

  const long long NN = (long long)TOK * ID;

  hipMemsetAsync(sums, 0, 16, stream);

  conv_bf16<<<8192, 256, 0, stream>>>(x,       xbf,  TOK * HD / 4);
  conv_bf16<<<8192, 256, 0, stream>>>(qw_gate, wgbf, ID * HD / 4);
  conv_bf16<<<8192, 256, 0, stream>>>(qw_up,   wubf, ID * HD / 4);
  conv_bf16<<<8192, 256, 0, stream>>>(qw_down, wdbf, HD * ID / 4);

  // gate GEMM + silu + sum|ga|
  gemm_bt<0><<<dim3(ID / 128, TOK / 128), 256, 0, stream>>>(
      xbf, wgbf, TOK, ID, HD, ga, nullptr, x_scale, ws_gate, sums, NN);

  // up GEMM + inter computation + sum|inter|
  gemm_bt<1><<<dim3(ID / 128, TOK / 128), 256, 0, stream>>>(
      xbf, wubf, TOK, ID, HD, inter, ga, x_scale, ws_up, sums, NN);

  // quantize inter -> bf16 int8-valued; also write scalar output
  quant_inter<<<8192, 256, 0, stream>>>(inter, interq, sums, NN, ws_down,
                                        out + (size_t)TOK * HD, (int)(NN / 4));

  // down GEMM -> final output
  gemm_bt<2><<<dim3(HD / 128, TOK / 128), 256, 0, stream>>>(
      interq, wdbf, TOK, HD, ID, out, nullptr, nullptr, nullptr, sums, NN);
}

// Round 2
// 1988.798 us; speedup vs baseline: 1.2358x; 1.2358x over previous
//
#include <hip/hip_runtime.h>
#include <math.h>

// Problem dims (fixed): B=2, S=2048 -> TOK=4096 tokens; H=4096; I=11008
#define TOK 4096
#define HD  4096
#define ID  11008

typedef int i32x4 __attribute__((ext_vector_type(4)));

#define GLDS16(g, l) __builtin_amdgcn_global_load_lds( \
    (const __attribute__((address_space(1))) void*)(g), \
    (__attribute__((address_space(3))) void*)(l), 16, 0, 0)

// ---------------------------------------------------------------- convert ---
// f32 -> int8. All values are exact small integers ({-1,0,1} weights,
// [-128,127] activations), so the cast is exact.
__global__ void conv_i8(const float* __restrict__ in,
                        char* __restrict__ out, int n4) {
  int stride = gridDim.x * blockDim.x;
  for (int i = blockIdx.x * blockDim.x + threadIdx.x; i < n4; i += stride) {
    float4 v = ((const float4*)in)[i];
    char4 o;
    o.x = (char)(int)rintf(v.x);
    o.y = (char)(int)rintf(v.y);
    o.z = (char)(int)rintf(v.z);
    o.w = (char)(int)rintf(v.w);
    ((char4*)out)[i] = o;
  }
}

// ----------------------------------------------------------------- GEMM -----
// out[m,n] = sum_k A[m,k]*B[n,k]  (both K-major int8), i32 accumulate (exact).
// 128x128 tile, 4 waves (2x2 of 64x64), 4x4 MFMA 16x16x64 i8 tiles per wave.
// LDS staged in FRAGMENT ORDER: 16B slot s = kchunk*128 + row  (kchunk = k/16
// within the 64-wide K stage). global_load_lds dest is lane-contiguous, which
// is exactly this layout; fragment ds_read_b128 is then bank-conflict-free
// (16 lanes -> 16 consecutive 16B chunks = 2-way/bank = free, m136).
// GROUP_M=8 block swizzle: 8 consecutive blocks share a B tile; A panel
// (8 x 512KB) stays L2-resident; B (43MB i8) fits L3.
// MODE 0: gate -> ga = silu(acc*gs), store f32, sum|ga| -> sums[0]
// MODE 1: up   -> inter = clip(rint(ga/ga_s))*acc*(ga_s*up_s), store f32,
//                 sum|inter| -> sums[1]
// MODE 2: down -> plain f32 store (exact integers)
template<int MODE>
__global__ __launch_bounds__(256)
void gemm_i8(const char* __restrict__ A,
             const char* __restrict__ Bm,
             int M, int N, int K,
             float* __restrict__ Cout,
             const float* __restrict__ ga_in,
             const float* __restrict__ sc0,
             const float* __restrict__ sc1,
             double* __restrict__ sums,
             long long NN)
{
  __shared__ char As[8192];   // 512 slots x 16B: slot = kchunk*128 + row
  __shared__ char Bs[8192];
  __shared__ double red[4];

  const int tid  = threadIdx.x;
  const int w    = tid >> 6;        // wave 0..3
  const int lane = tid & 63;
  const int wr   = lane & 15;
  const int qd   = lane >> 4;
  const int wm   = (w >> 1) << 6;
  const int wn   = (w & 1) << 6;

  // GROUP_M=8 swizzle (m-tile count is 32 for all three GEMMs: divisible)
  const int nbx = gridDim.x;
  const int L   = blockIdx.y * nbx + blockIdx.x;
  const int per = nbx << 3;
  const int grp = L / per;
  const int rem = L - grp * per;
  const int tm  = (grp << 3) + (rem & 7);
  const int tn  = rem >> 3;
  const int m0  = tm << 7;
  const int n0  = tn << 7;

  i32x4 acc[4][4] = {};

  // staging: thread t fills slot t (call 1) and slot t+256 (call 2).
  // slot s: row = s&127, kchunk = s>>7. Source byte = row*K + kchunk*16.
  const int rowL = tid & 127;
  const int kcL  = tid >> 7;        // 0 or 1; call 2 adds 2 -> +32 bytes
  const char* gA = A  + (size_t)(m0 + rowL) * K + (kcL << 4);
  const char* gB = Bm + (size_t)(n0 + rowL) * K + (kcL << 4);
  char* lA = As + (w << 10);        // wave-uniform base: slots [w*64, w*64+64)
  char* lB = Bs + (w << 10);

  for (int k0 = 0; k0 < K; k0 += 64) {
    GLDS16(gA + k0,      lA);
    GLDS16(gA + k0 + 32, lA + 4096);
    GLDS16(gB + k0,      lB);
    GLDS16(gB + k0 + 32, lB + 4096);
    __syncthreads();

    i32x4 af[4], bfr[4];
#pragma unroll
    for (int i = 0; i < 4; i++)
      af[i] = *(const i32x4*)(As + (((qd << 7) + wm + (i << 4) + wr) << 4));
#pragma unroll
    for (int j = 0; j < 4; j++)
      bfr[j] = *(const i32x4*)(Bs + (((qd << 7) + wn + (j << 4) + wr) << 4));

#pragma unroll
    for (int i = 0; i < 4; i++)
#pragma unroll
      for (int j = 0; j < 4; j++)
        acc[i][j] = __builtin_amdgcn_mfma_i32_16x16x64_i8(af[i], bfr[j],
                                                          acc[i][j], 0, 0, 0);
    __syncthreads();
  }

  // epilogue: C/D layout col = lane&15 (n), row = quad*4 + reg (m)
  double lsum = 0.0;

  if (MODE == 0) {
    const float gs = sc0[0] * sc1[0];
#pragma unroll
    for (int i = 0; i < 4; i++) {
      const int mb = m0 + wm + (i << 4) + (qd << 2);
#pragma unroll
      for (int j = 0; j < 4; j++) {
        const int n = n0 + wn + (j << 4) + wr;
#pragma unroll
        for (int r = 0; r < 4; r++) {
          float g = (float)acc[i][j][r] * gs;
          float s = g / (1.0f + expf(-g));          // silu
          Cout[(size_t)(mb + r) * N + n] = s;
          lsum += (double)fabsf(s);
        }
      }
    }
  } else if (MODE == 1) {
    const float up_s  = sc0[0] * sc1[0];
    const float ga_s  = (float)(sums[0] / (double)NN) + 1e-8f;
    const float combo = ga_s * up_s;
#pragma unroll
    for (int i = 0; i < 4; i++) {
      const int mb = m0 + wm + (i << 4) + (qd << 2);
#pragma unroll
      for (int j = 0; j < 4; j++) {
        const int n = n0 + wn + (j << 4) + wr;
#pragma unroll
        for (int r = 0; r < 4; r++) {
          float up = (float)acc[i][j][r];
          float ga = ga_in[(size_t)(mb + r) * N + n];
          float gq = fmaxf(-128.0f, fminf(127.0f, rintf(ga / ga_s)));
          float itv = gq * up * combo;              // same assoc as reference
          Cout[(size_t)(mb + r) * N + n] = itv;
          lsum += (double)fabsf(itv);
        }
      }
    }
  } else {
#pragma unroll
    for (int i = 0; i < 4; i++) {
      const int mb = m0 + wm + (i << 4) + (qd << 2);
#pragma unroll
      for (int j = 0; j < 4; j++) {
        const int n = n0 + wn + (j << 4) + wr;
#pragma unroll
        for (int r = 0; r < 4; r++)
          Cout[(size_t)(mb + r) * N + n] = (float)acc[i][j][r];
      }
    }
  }

  if (MODE != 2) {
    for (int off = 32; off; off >>= 1) lsum += __shfl_down(lsum, off, 64);
    if (lane == 0) red[w] = lsum;
    __syncthreads();
    if (tid == 0) atomicAdd(&sums[MODE], red[0] + red[1] + red[2] + red[3]);
  }
}

// ------------------------------------------------------------- quantize -----
__global__ void quant_inter(const float* __restrict__ inter,
                            char* __restrict__ outq,
                            const double* __restrict__ sums, long long NN,
                            const float* __restrict__ wsd,
                            float* __restrict__ scalar_out, int n4)
{
  const float is = (float)(sums[1] / (double)NN) + 1e-8f;
  if (blockIdx.x == 0 && threadIdx.x == 0) scalar_out[0] = is * wsd[0];
  int stride = gridDim.x * blockDim.x;
  for (int i = blockIdx.x * blockDim.x + threadIdx.x; i < n4; i += stride) {
    float4 v = ((const float4*)inter)[i];
    char4 o;
    o.x = (char)(int)fmaxf(-128.0f, fminf(127.0f, rintf(v.x / is)));
    o.y = (char)(int)fmaxf(-128.0f, fminf(127.0f, rintf(v.y / is)));
    o.z = (char)(int)fmaxf(-128.0f, fminf(127.0f, rintf(v.z / is)));
    o.w = (char)(int)fmaxf(-128.0f, fminf(127.0f, rintf(v.w / is)));
    ((char4*)outq)[i] = o;
  }
}

// ---------------------------------------------------------------- launch ----
extern "C" void kernel_launch(void* const* d_in, const int* in_sizes, int n_in,
                              void* d_out, int out_size, void* d_ws, size_t ws_size,
                              hipStream_t stream) {
  const float* x        = (const float*)d_in[0];
  const float* x_scale  = (const float*)d_in[1];
  const float* qw_gate  = (const float*)d_in[2];
  const float* ws_gate  = (const float*)d_in[3];
  const float* qw_up    = (const float*)d_in[4];
  const float* ws_up    = (const float*)d_in[5];
  const float* qw_down  = (const float*)d_in[6];
  const float* ws_down  = (const float*)d_in[7];
  float* out = (float*)d_out;

  char* ws = (char*)d_ws;
  double* sums = (double*)ws;                 // [0]=sum|ga| [1]=sum|inter|
  size_t off = 256;
  char* xq     = ws + off; off += (size_t)TOK * HD;
  char* wgq    = ws + off; off += (size_t)ID * HD;
  char* wuq    = ws + off; off += (size_t)ID * HD;
  char* wdq    = ws + off; off += (size_t)HD * ID;
  char* interq = ws + off; off += (size_t)TOK * ID;
  float* ga    = (float*)(ws + off); off += (size_t)TOK * ID * 4;
  float* inter = (float*)(ws + off); off += (size_t)TOK * ID * 4;

  const long long NN = (long long)TOK * ID;

  hipMemsetAsync(sums, 0, 16, stream);

  conv_i8<<<4096, 256, 0, stream>>>(x,       xq,  TOK * HD / 4);
  conv_i8<<<8192, 256, 0, stream>>>(qw_gate, wgq, ID * HD / 4);
  conv_i8<<<8192, 256, 0, stream>>>(qw_up,   wuq, ID * HD / 4);
  conv_i8<<<8192, 256, 0, stream>>>(qw_down, wdq, HD * ID / 4);

  // gate GEMM + silu + sum|ga|
  gemm_i8<0><<<dim3(ID / 128, TOK / 128), 256, 0, stream>>>(
      xq, wgq, TOK, ID, HD, ga, nullptr, x_scale, ws_gate, sums, NN);

  // up GEMM + inter computation + sum|inter|
  gemm_i8<1><<<dim3(ID / 128, TOK / 128), 256, 0, stream>>>(
      xq, wuq, TOK, ID, HD, inter, ga, x_scale, ws_up, sums, NN);

  // quantize inter -> int8; also write scalar output
  quant_inter<<<8192, 256, 0, stream>>>(inter, interq, sums, NN, ws_down,
                                        out + (size_t)TOK * HD, (int)(NN / 4));

  // down GEMM -> final output (exact integers in f32)
  gemm_i8<2><<<dim3(HD / 128, TOK / 128), 256, 0, stream>>>(
      interq, wdq, TOK, HD, ID, out, nullptr, nullptr, nullptr, sums, NN);
}